// Round 7
// baseline (160.330 us; speedup 1.0000x reference)
//
#include <hip/hip_runtime.h>
#include <math.h>

#define DIM 128
#define TEMP_INV 10.0f
#define LOG2E 1.4426950408889634f
#define SPLIT 4               // blocks per anchor in the loss kernel

typedef __attribute__((ext_vector_type(2))) float floatx2;

// ---------------- fp8 fast path ----------------
// Normalize rows and quantize to fp8 e4m3 (OCP, HW cvt): one 32-lane group
// per row; lane holds 4 floats -> packs 4 fp8 into one uint.
// Also zeroes d_out[0] and the per-anchor partial arrays (harness re-poisons
// out/ws to 0xAA before every timed replay).
__global__ __launch_bounds__(256) void norm_fp8_kernel(const float* __restrict__ x,
                                                       unsigned int* __restrict__ xq,
                                                       float* __restrict__ partials,
                                                       int A3,
                                                       float* __restrict__ out,
                                                       int N) {
    int gtid = blockIdx.x * 256 + threadIdx.x;
    if (gtid == 0) out[0] = 0.0f;
    if (gtid < A3) partials[gtid] = 0.0f;

    int lane = threadIdx.x & 31;
    int grp  = threadIdx.x >> 5;
    int row  = blockIdx.x * 8 + grp;
    if (row >= N) return;
    float4 v = *(const float4*)(x + (size_t)row * DIM + lane * 4);
    float s = v.x*v.x + v.y*v.y + v.z*v.z + v.w*v.w;
    s += __shfl_xor(s, 16); s += __shfl_xor(s, 8); s += __shfl_xor(s, 4);
    s += __shfl_xor(s, 2);  s += __shfl_xor(s, 1);
    float inv = rsqrtf(s);
    int p = 0;
    p = __builtin_amdgcn_cvt_pk_fp8_f32(v.x * inv, v.y * inv, p, false);
    p = __builtin_amdgcn_cvt_pk_fp8_f32(v.z * inv, v.w * inv, p, true);
    xq[(size_t)row * 32 + lane] = (unsigned int)p;
}

static __device__ __forceinline__ float dot16_fp8(const uint4& r, const float* av) {
    floatx2 t;
    float d = 0.0f;
    t = __builtin_amdgcn_cvt_pk_f32_fp8((int)r.x, false); d += av[0]*t.x  + av[1]*t.y;
    t = __builtin_amdgcn_cvt_pk_f32_fp8((int)r.x, true);  d += av[2]*t.x  + av[3]*t.y;
    t = __builtin_amdgcn_cvt_pk_f32_fp8((int)r.y, false); d += av[4]*t.x  + av[5]*t.y;
    t = __builtin_amdgcn_cvt_pk_f32_fp8((int)r.y, true);  d += av[6]*t.x  + av[7]*t.y;
    t = __builtin_amdgcn_cvt_pk_f32_fp8((int)r.z, false); d += av[8]*t.x  + av[9]*t.y;
    t = __builtin_amdgcn_cvt_pk_f32_fp8((int)r.z, true);  d += av[10]*t.x + av[11]*t.y;
    t = __builtin_amdgcn_cvt_pk_f32_fp8((int)r.w, false); d += av[12]*t.x + av[13]*t.y;
    t = __builtin_amdgcn_cvt_pk_f32_fp8((int)r.w, true);  d += av[14]*t.x + av[15]*t.y;
    return d;
}

// Grid = A*SPLIT blocks; block = anchor (blockIdx>>2), quarter (blockIdx&3),
// spb=128 samples. 256 thr = 4 waves; wave owns 32 samples = 8 groups x 4.
// MLP fix: rows are gathered with global_load_lds (LDS-DMA, no VGPR dest,
// issued where written -> 4 instrs x 8 rows in flight per wave, guaranteed;
// R4-R6 register-destination forms all collapsed to MLP=1, VGPR=28).
// Layout: staging instr j writes lane L's 16B to wavebuf + j*1024 + L*16,
// so sample (j*8+g) sits at wavebuf + j*1024 + g*128 (g=L>>3, k=L&7).
__global__ __launch_bounds__(256, 8) void loss_fp8_kernel(const unsigned int* __restrict__ xq,
                                                          const int* __restrict__ y,
                                                          const int* __restrict__ anchors,
                                                          const int* __restrict__ sampled,
                                                          float* __restrict__ p_num,
                                                          float* __restrict__ p_den,
                                                          float* __restrict__ p_cnt,
                                                          int S) {
    int a    = blockIdx.x >> 2;       // anchor
    int q    = blockIdx.x & 3;        // quarter
    int tid  = threadIdx.x;
    int wave = tid >> 6;              // 0..3
    int lane = tid & 63;
    int g    = lane >> 3;             // 0..7  group within wave
    int k    = lane & 7;              // chunk within row

    __shared__ __align__(16) char stage[4 * 4096];   // 4 waves x 4 instr x 1024B
    __shared__ int s_pk[128];                        // (sidx<<1) | pos

    int anchor = anchors[a];
    int ya     = y[anchor];

    const int* samp = sampled + (size_t)a * S + (size_t)q * 128;
    if (tid < 128) {
        int si = samp[tid];                          // coalesced
        s_pk[tid] = (si << 1) | (y[si] == ya ? 1 : 0); // divergent y gather (L2)
    }

    // anchor row: 16 fp8 -> 16 floats, prescaled by log2e/temp (exp2 path)
    uint4 ar = *(const uint4*)(xq + (size_t)anchor * 32 + k * 4 + (g & 1) * 0);
    float av[16];
    {
        floatx2 t;
        t = __builtin_amdgcn_cvt_pk_f32_fp8((int)ar.x, false); av[0]=t.x;  av[1]=t.y;
        t = __builtin_amdgcn_cvt_pk_f32_fp8((int)ar.x, true);  av[2]=t.x;  av[3]=t.y;
        t = __builtin_amdgcn_cvt_pk_f32_fp8((int)ar.y, false); av[4]=t.x;  av[5]=t.y;
        t = __builtin_amdgcn_cvt_pk_f32_fp8((int)ar.y, true);  av[6]=t.x;  av[7]=t.y;
        t = __builtin_amdgcn_cvt_pk_f32_fp8((int)ar.z, false); av[8]=t.x;  av[9]=t.y;
        t = __builtin_amdgcn_cvt_pk_f32_fp8((int)ar.z, true);  av[10]=t.x; av[11]=t.y;
        t = __builtin_amdgcn_cvt_pk_f32_fp8((int)ar.w, false); av[12]=t.x; av[13]=t.y;
        t = __builtin_amdgcn_cvt_pk_f32_fp8((int)ar.w, true);  av[14]=t.x; av[15]=t.y;
        const float sc = TEMP_INV * LOG2E;
#pragma unroll
        for (int j = 0; j < 16; ++j) av[j] *= sc;
    }
    __syncthreads();

    // ---- stage: 4 LDS-DMA gathers, 8 rows each, all in flight ----
    int wbase = wave * 32;
    const char* xqb = (const char*)xq;
    char* wavebuf = stage + wave * 4096;
    int pk[4];
#pragma unroll
    for (int j = 0; j < 4; ++j) {
        pk[j] = s_pk[wbase + j * 8 + g];
        const void* gp = xqb + (size_t)(pk[j] >> 1) * 128 + k * 16;
        void* lp = wavebuf + j * 1024;               // wave-uniform base
        __builtin_amdgcn_global_load_lds((const __attribute__((address_space(1))) void*)gp,
                                         (__attribute__((address_space(3))) void*)lp,
                                         16, 0, 0);
    }
    asm volatile("s_waitcnt vmcnt(0)" ::: "memory");

    // ---- compute: read rows back (conflict-free), dot + exp ----
    float num = 0.0f, den = 0.0f, cnt = 0.0f;
#pragma unroll
    for (int j = 0; j < 4; ++j) {
        const uint4 sr = *(const uint4*)(wavebuf + j * 1024 + g * 128 + k * 16);
        float d = dot16_fp8(sr, av);
        d += __shfl_xor(d, 4); d += __shfl_xor(d, 2); d += __shfl_xor(d, 1);
        float e = exp2f(d);               // d = sim*log2e/temp already
        den += e;
        bool pos = (pk[j] & 1);
        num += pos ? e : 0.0f;  cnt += pos ? 1.0f : 0.0f;
    }

    // lanes within an 8-lane group identical; butterfly across the 8 groups
    num += __shfl_xor(num, 8);  den += __shfl_xor(den, 8);  cnt += __shfl_xor(cnt, 8);
    num += __shfl_xor(num, 16); den += __shfl_xor(den, 16); cnt += __shfl_xor(cnt, 16);
    num += __shfl_xor(num, 32); den += __shfl_xor(den, 32); cnt += __shfl_xor(cnt, 32);
    if (lane == 0) {
        atomicAdd(p_num + a, num);
        atomicAdd(p_den + a, den);
        atomicAdd(p_cnt + a, cnt);
    }
}

// Per-anchor log + global sum. One thread per anchor.
__global__ __launch_bounds__(256) void finalize_kernel(const float* __restrict__ p_num,
                                                       const float* __restrict__ p_den,
                                                       const float* __restrict__ p_cnt,
                                                       float* __restrict__ out,
                                                       int A) {
    int a = blockIdx.x * 256 + threadIdx.x;
    float loss = 0.0f;
    if (a < A) {
        float tc = p_cnt[a];
        if (tc > 0.0f) loss = -__logf(p_num[a] / p_den[a]) / tc;
    }
    loss += __shfl_xor(loss, 1);  loss += __shfl_xor(loss, 2);
    loss += __shfl_xor(loss, 4);  loss += __shfl_xor(loss, 8);
    loss += __shfl_xor(loss, 16); loss += __shfl_xor(loss, 32);
    if ((threadIdx.x & 63) == 0) atomicAdd(out, loss);
}

// ---------------- fp32 fallback (used only if ws too small / odd shape) -----

__global__ __launch_bounds__(256) void norm_kernel(const float* __restrict__ x,
                                                   float* __restrict__ inv_norm,
                                                   float* __restrict__ out,
                                                   int N) {
    if (blockIdx.x == 0 && threadIdx.x == 0) out[0] = 0.0f;
    int wave = threadIdx.x >> 6;
    int lane = threadIdx.x & 63;
    int row  = blockIdx.x * 4 + wave;
    if (row >= N) return;
    const float2 v = *(const float2*)(x + (size_t)row * DIM + lane * 2);
    float s = v.x * v.x + v.y * v.y;
    s += __shfl_xor(s, 32); s += __shfl_xor(s, 16); s += __shfl_xor(s, 8);
    s += __shfl_xor(s, 4);  s += __shfl_xor(s, 2);  s += __shfl_xor(s, 1);
    if (lane == 0) inv_norm[row] = rsqrtf(s);
}

__global__ __launch_bounds__(256) void loss_kernel(const float* __restrict__ x,
                                                   const int* __restrict__ y,
                                                   const int* __restrict__ anchors,
                                                   const int* __restrict__ sampled,
                                                   const float* __restrict__ inv_norm,
                                                   float* __restrict__ out,
                                                   int S) {
    int a     = blockIdx.x;
    int tid   = threadIdx.x;
    int lane  = tid & 31;
    int group = tid >> 5;

    int   anchor = anchors[a];
    int   ya     = y[anchor];
    float inv_a  = inv_norm[anchor];
    float4 av = *(const float4*)(x + (size_t)anchor * DIM + lane * 4);
    av.x *= inv_a; av.y *= inv_a; av.z *= inv_a; av.w *= inv_a;

    float num = 0.0f, den = 0.0f, cnt = 0.0f;
    const int* samp = sampled + (size_t)a * S;

#pragma unroll 4
    for (int s = group; s < S; s += 8) {
        int   sidx  = samp[s];
        float inv_s = inv_norm[sidx];
        int   ys    = y[sidx];
        const float4 sv = *(const float4*)(x + (size_t)sidx * DIM + lane * 4);
        float d = av.x * sv.x + av.y * sv.y + av.z * sv.z + av.w * sv.w;
        d += __shfl_xor(d, 16); d += __shfl_xor(d, 8); d += __shfl_xor(d, 4);
        d += __shfl_xor(d, 2);  d += __shfl_xor(d, 1);
        float e = __expf(d * inv_s * TEMP_INV);
        den += e;
        bool pos = (ys == ya);
        num += pos ? e : 0.0f;
        cnt += pos ? 1.0f : 0.0f;
    }

    __shared__ float s_num[8], s_den[8], s_cnt[8];
    if (lane == 0) { s_num[group] = num; s_den[group] = den; s_cnt[group] = cnt; }
    __syncthreads();
    if (tid == 0) {
        float tn = 0.0f, td = 0.0f, tc = 0.0f;
        for (int g = 0; g < 8; ++g) { tn += s_num[g]; td += s_den[g]; tc += s_cnt[g]; }
        float loss = 0.0f;
        if (tc > 0.0f) loss = -__logf(tn / td) / tc;
        atomicAdd(out, loss);
    }
}

extern "C" void kernel_launch(void* const* d_in, const int* in_sizes, int n_in,
                              void* d_out, int out_size, void* d_ws, size_t ws_size,
                              hipStream_t stream) {
    const float* x       = (const float*)d_in[0];
    const int*   y       = (const int*)d_in[1];
    const int*   anchors = (const int*)d_in[2];
    const int*   sampled = (const int*)d_in[3];

    int N = in_sizes[1];
    int A = in_sizes[2];
    int S = in_sizes[3] / A;

    float* out = (float*)d_out;
    size_t need_fp8 = (size_t)N * DIM + (size_t)3 * A * sizeof(float);

    if (ws_size >= need_fp8 && S == 512) {
        unsigned int* xq = (unsigned int*)d_ws;
        float* partials  = (float*)((char*)d_ws + (size_t)N * DIM);
        float* p_num = partials;
        float* p_den = partials + A;
        float* p_cnt = partials + 2 * A;

        int nblocks = (N + 7) / 8;
        norm_fp8_kernel<<<nblocks, 256, 0, stream>>>(x, xq, partials, 3 * A, out, N);
        loss_fp8_kernel<<<A * SPLIT, 256, 0, stream>>>(xq, y, anchors, sampled,
                                                       p_num, p_den, p_cnt, S);
        finalize_kernel<<<(A + 255) / 256, 256, 0, stream>>>(p_num, p_den, p_cnt, out, A);
    } else {
        float* inv_norm = (float*)d_ws;
        int nblocks = (N + 3) / 4;
        norm_kernel<<<nblocks, 256, 0, stream>>>(x, inv_norm, out, N);
        loss_kernel<<<A, 256, 0, stream>>>(x, y, anchors, sampled, inv_norm, out, S);
    }
}